// Round 3
// baseline (77.038 us; speedup 1.0000x reference)
//
#include <hip/hip_runtime.h>

#define NBOX   2048
#define HALF   1024
#define MAXDET 100
#define NIMG   8
#define POOL   256
// midpoint(0.3f, nextafterf(0.3f,+inf)) in double:
// RN_f32(inter/denom) > 0.3f  <=>  inter > IOU_MID * denom
// (25-bit mid x 24-bit denom product exact in f64; tie rounds-to-even to 0.3f -> "false" matches)
#define IOU_MID 0x1.333335p-2

typedef unsigned long long u64;

__device__ __forceinline__ u64 shx64(u64 v, int m) {
    int lo = __shfl_xor((int)(unsigned int)v, m, 64);
    int hi = __shfl_xor((int)(unsigned int)(v >> 32), m, 64);
    return ((u64)(unsigned int)hi << 32) | (unsigned int)lo;
}
// bitonic keep rule: take_max ? max(mine, part) : min(mine, part); keys unique
__device__ __forceinline__ u64 cmpsel(u64 mine, u64 part, bool take_max) {
    return ((mine > part) == take_max) ? mine : part;
}
__device__ __forceinline__ u64 readlane64(u64 v, int l) {
    unsigned int lo = (unsigned int)__builtin_amdgcn_readlane((int)(unsigned int)v, l);
    unsigned int hi = (unsigned int)__builtin_amdgcn_readlane((int)(v >> 32), l);
    return ((u64)hi << 32) | lo;
}
__device__ __forceinline__ u64 mkkey(float4 v, float s, int i) {
    bool valid = ((v.z - v.x) >= 25.0f) && ((v.w - v.y) >= 25.0f) && (s >= 0.001f);
    unsigned int sk = valid ? __float_as_uint(s) : 0u;  // scores in [0,1): bits monotone
    return ((u64)sk << 32) | (unsigned int)(~i);
}

// One block per image, 1024 threads (16 waves). R21: threads 0-511 sort with
// 4 CONSECUTIVE keys each (256 threads/half) -> element exchanges j=1,2 are
// register swaps, j=4..128 intra-wave shuffles (lane-xor j/4), only j=256,512
// need LDS: 3 LDS stages + publish = 4 barriers (was 7). Stage buffers are
// SoA-indexed (u + 256*r) for 8B/lane stride (2-way bank alias = free).
// Meanwhile waves 8-15 stage all 2048 boxes into LDS; the sbox gather and the
// tail's candidate loads become LDS reads. Prune-merge (R15), matrix (R10),
// scan (R18), batched tail (R19) otherwise unchanged.
__global__ __launch_bounds__(1024) void k_all(
    const float* __restrict__ boxes, const float* __restrict__ scores,
    float* __restrict__ out)
{
    __shared__ u64    bufA[NBOX];         // 16 KB; ends holding both sorted halves (linear)
    __shared__ u64    bufB[NBOX];         // 16 KB; sort double buffer
    __shared__ float4 boxLds[NBOX];       // 32 KB; all input boxes (staged by waves 8-15)
    __shared__ u64    supRow[POOL * 4];   // 8 KB suppression matrix (bits j>i only)
    __shared__ float4 sbox[POOL];         // 4 KB sorted top-256 boxes
    __shared__ u64    mA[POOL], mB[POOL]; // merge scratch (4 KB)
    __shared__ u64    validW[4];
    __shared__ u64    pminS;
    __shared__ int    kposL[MAXDET];      // keeper positions (sorted order)
    __shared__ float4 leadersB[MAXDET];
    __shared__ float  leadersA[MAXDET];

    const int g    = threadIdx.x;         // 0..1023
    const int lane = g & 63;
    const int wv   = g >> 6;              // 0..15
    const int img  = blockIdx.x;
    const float4* bb4 = (const float4*)boxes + img * NBOX;
    const float*  ss  = scores + img * NBOX;

#define SWAP1(a, b, D) { if ((D) ? ((a) < (b)) : ((a) > (b))) { u64 t_ = (a); (a) = (b); (b) = t_; } }

    // ---- Sort (threads 0-511) + box staging (threads 512-1023), overlapped.
    // Sorting layout: u = g&255 (thread within half), hb = half base (0|HALF),
    // keys k0..k3 = elements hb+4u..hb+4u+3. Bitonic stage K, j=K/2..1,
    // dir(e) = ((e&K)==0); j=1,2 in regs, j=4..128 shuffles (m=j/4),
    // j=256 (u^64), j=512 (u^128) via LDS.
    u64 k0 = 0, k1 = 0, k2 = 0, k3 = 0;
    int u = 0, hb = 0, base = 0;
    if (g < 512) {
        u = g & 255; hb = (g >> 8) * HALF; base = hb + (u << 2);
        float4 sc = *((const float4*)(ss + base));   // 4 consecutive scores
        { float4 v = bb4[base + 0]; k0 = mkkey(v, sc.x, base + 0); }
        { float4 v = bb4[base + 1]; k1 = mkkey(v, sc.y, base + 1); }
        { float4 v = bb4[base + 2]; k2 = mkkey(v, sc.z, base + 2); }
        { float4 v = bb4[base + 3]; k3 = mkkey(v, sc.w, base + 3); }
        // K=2 (j=1): pair (4u,4u+1) desc (e&2==0), pair (4u+2,4u+3) asc.
        SWAP1(k0, k1, true) SWAP1(k2, k3, false)
        // K=4 (j=2,1): dir = ((e&4)==0) = ((u&1)==0).
        { bool D = ((u & 1) == 0); SWAP1(k0, k2, D) SWAP1(k1, k3, D) SWAP1(k0, k1, D) SWAP1(k2, k3, D) }
        // K=8..256: K4=K/4: dir=((u&K4)==0); shuffles m=K4/2..1 (j=4m); then j=2,1.
        for (int K4 = 2; K4 <= 64; K4 <<= 1) {
            bool D = ((u & K4) == 0);
            for (int m = K4 >> 1; m >= 1; m >>= 1) {
                bool tm = (D == ((lane & m) == 0));
                k0 = cmpsel(k0, shx64(k0, m), tm); k1 = cmpsel(k1, shx64(k1, m), tm);
                k2 = cmpsel(k2, shx64(k2, m), tm); k3 = cmpsel(k3, shx64(k3, m), tm);
            }
            SWAP1(k0, k2, D) SWAP1(k1, k3, D) SWAP1(k0, k1, D) SWAP1(k2, k3, D)
        }
        // K=512 stage, j=256 exchange: write SoA to bufB.
        bufB[hb + u]       = k0;
        bufB[hb + 256 + u] = k1;
        bufB[hb + 512 + u] = k2;
        bufB[hb + 768 + u] = k3;
    } else {
        int b0 = g - 512;                 // stage all 2048 boxes, coalesced
        boxLds[b0]        = bb4[b0];
        boxLds[b0 + 512]  = bb4[b0 + 512];
        boxLds[b0 + 1024] = bb4[b0 + 1024];
        boxLds[b0 + 1536] = bb4[b0 + 1536];
    }
    __syncthreads();
    if (g < 512) {                        // K=512: j=256 (LDS), 128..4 (shfl), 2,1 (reg)
        bool D = ((u & 128) == 0);        // dir = ((e&512)==0)
        int pu = u ^ 64;
        bool tm = (D == ((u & 64) == 0));
        k0 = cmpsel(k0, bufB[hb + pu], tm);       k1 = cmpsel(k1, bufB[hb + 256 + pu], tm);
        k2 = cmpsel(k2, bufB[hb + 512 + pu], tm); k3 = cmpsel(k3, bufB[hb + 768 + pu], tm);
        for (int m = 32; m >= 1; m >>= 1) {
            bool t2 = (D == ((lane & m) == 0));
            k0 = cmpsel(k0, shx64(k0, m), t2); k1 = cmpsel(k1, shx64(k1, m), t2);
            k2 = cmpsel(k2, shx64(k2, m), t2); k3 = cmpsel(k3, shx64(k3, m), t2);
        }
        SWAP1(k0, k2, D) SWAP1(k1, k3, D) SWAP1(k0, k1, D) SWAP1(k2, k3, D)
        // K=1024 stage, j=512 exchange: write SoA to bufA.
        bufA[hb + u]       = k0;
        bufA[hb + 256 + u] = k1;
        bufA[hb + 512 + u] = k2;
        bufA[hb + 768 + u] = k3;
    }
    __syncthreads();
    if (g < 512) {                        // K=1024 (dir=true): j=512 exchange
        int pu = u ^ 128;
        bool tm = ((u & 128) == 0);
        k0 = cmpsel(k0, bufA[hb + pu], tm);       k1 = cmpsel(k1, bufA[hb + 256 + pu], tm);
        k2 = cmpsel(k2, bufA[hb + 512 + pu], tm); k3 = cmpsel(k3, bufA[hb + 768 + pu], tm);
        bufB[hb + u]       = k0;          // j=256 exchange staging
        bufB[hb + 256 + u] = k1;
        bufB[hb + 512 + u] = k2;
        bufB[hb + 768 + u] = k3;
    }
    __syncthreads();
    if (g < 512) {                        // K=1024: j=256 (LDS), 128..4, 2,1; publish linear
        int pu = u ^ 64;
        bool tm = ((u & 64) == 0);
        k0 = cmpsel(k0, bufB[hb + pu], tm);       k1 = cmpsel(k1, bufB[hb + 256 + pu], tm);
        k2 = cmpsel(k2, bufB[hb + 512 + pu], tm); k3 = cmpsel(k3, bufB[hb + 768 + pu], tm);
        for (int m = 32; m >= 1; m >>= 1) {
            bool t2 = ((lane & m) == 0);
            k0 = cmpsel(k0, shx64(k0, m), t2); k1 = cmpsel(k1, shx64(k1, m), t2);
            k2 = cmpsel(k2, shx64(k2, m), t2); k3 = cmpsel(k3, shx64(k3, m), t2);
        }
        SWAP1(k0, k2, true) SWAP1(k1, k3, true) SWAP1(k0, k1, true) SWAP1(k2, k3, true)
        bufA[base + 0] = k0; bufA[base + 1] = k1;   // linear publish for hk consumers
        bufA[base + 2] = k2; bufA[base + 3] = k3;
    }
    __syncthreads();

    const u64* hk = bufA;   // sorted halves, LDS-resident (linear)

    // Top-256 prune-merge (R15-proven): C[e] = max(A[e], B[255-e]) is the
    // top-256 multiset and bitonic; descending merge: take_max iff (e&j)==0.
    u64 c = 0;
    if (g < POOL) {
        u64 a  = hk[g];
        u64 bq = hk[HALF + (POOL - 1 - g)];
        c = (a > bq) ? a : bq;
        mA[g] = c;
    }
    __syncthreads();
    if (g < POOL) { c = cmpsel(c, mA[g ^ 128], (g & 128) == 0); mB[g] = c; }
    __syncthreads();
    if (g < POOL) {                      // waves 0..3 fully active: ballot safe
        c = cmpsel(c, mB[g ^ 64], (g & 64) == 0);
        for (int m = 32; m >= 1; m >>= 1)
            c = cmpsel(c, shx64(c, m), (lane & m) == 0);
        unsigned int idx = ~(unsigned int)c;
        float4 v = boxLds[idx];          // LDS gather (was scattered global)
        sbox[g] = v;
        u64 bal = __ballot(((unsigned int)(c >> 32)) != 0u);
        if (lane == 0) validW[wv] = bal;
        if (g == POOL - 1) pminS = c;
    }
    __syncthreads();

    // Column cache: lane holds boxes at sorted positions 64*w + lane, w = 0..3.
    float4 cb[4];
    float  ca[4];
#pragma unroll
    for (int w = 0; w < 4; ++w) {
        float4 v = sbox[(w << 6) + lane];
        cb[w] = v;
        ca[w] = (v.z - v.x) * (v.w - v.y);
    }

    // Matrix build (R10-proven row math), 16 waves: wave wv owns rows i = 16r + wv.
    // supRow[i][w] bit l = (64w+l > i) && IoU(box_i, box_{64w+l}) > 0.3 (exact).
    // Words w < i>>6 left unwritten; never consumed.
    for (int r = 0; r < POOL / 16; ++r) {
        int i = (r << 4) + wv;
        float4 Li = sbox[i];              // wave-uniform broadcast read
        float La = (Li.z - Li.x) * (Li.w - Li.y);
        int w0 = i >> 6;                  // wave-uniform
#pragma unroll
        for (int w = 0; w < 4; ++w) {
            if (w >= w0) {                // wave-uniform condition: ballot safe
                int j0 = (w << 6) + lane;
                float iw = fminf(Li.z, cb[w].z) - fmaxf(Li.x, cb[w].x);
                float ih = fminf(Li.w, cb[w].w) - fmaxf(Li.y, cb[w].y);
                iw = fmaxf(iw, 0.0f);
                ih = fmaxf(ih, 0.0f);
                float inter = iw * ih;
                float denom = (La + ca[w]) - inter;   // ref op order: (a_i + a_j) - inter
                bool hit = (j0 > i) && ((double)inter > IOU_MID * (double)denom);
                u64 bits = __ballot(hit);
                if (lane == 0) supRow[(i << 2) + w] = bits;
            }
        }
    }
    __syncthreads();

    if (g >= 64) return;   // wave 0 finishes alone; no barriers below

    float* regions = out;
    float* maskv   = out + (size_t)NIMG * MAXDET * 5;

    // ---- Scan (R18-proven): pure SALU/readlane chain. Lane l preloads the
    // diagonal word of row (s<<6)+l for each segment; the keeper chain is
    // ctz -> v_readlane -> andn (no LDS). kposL records keepers (off-chain
    // ds_write); pend (word lane&3) is folded ONLY at segment boundaries from
    // the new keepers' rows, 64 lanes in parallel + shuffle-OR butterfly.
    u64 rd0 = supRow[(((0 << 6) + lane) << 2) + 0];
    u64 rd1 = supRow[(((1 << 6) + lane) << 2) + 1];
    u64 rd2 = supRow[(((2 << 6) + lane) << 2) + 2];
    u64 rd3 = supRow[(((3 << 6) + lane) << 2) + 3];

    int nkept = 0;
    u64 pend = 0;          // lane accumulates word (lane & 3)
#pragma unroll
    for (int s = 0; s < 4; ++s) {
        u64 rds = (s == 0) ? rd0 : (s == 1) ? rd1 : (s == 2) ? rd2 : rd3;
        u64 mcur = validW[s] & ~readlane64(pend, s);
        int n0 = nkept;
        while (mcur != 0ULL) {
            int il = (int)__builtin_ctzll(mcur);       // uniform (SALU)
            if (lane == 0) kposL[nkept] = (s << 6) + il;
            nkept++;
            if (nkept >= MAXDET) break;
            u64 rowS = readlane64(rds, il);            // register broadcast
            mcur = (mcur & (mcur - 1)) & ~rowS;        // bits j<=i of rowS are 0
        }
        if (nkept >= MAXDET) break;
        if (s < 3) {
            // fold new keepers' rows: lane group 4q..4q+3 covers keeper q's words
            for (int t = n0 + (lane >> 2); t < nkept; t += 16)
                pend |= supRow[(kposL[t] << 2) + (lane & 3)];
            pend |= shx64(pend, 4);
            pend |= shx64(pend, 8);
            pend |= shx64(pend, 16);
            pend |= shx64(pend, 32);   // now uniform within each mod-4 lane group
        }
    }

    // ---- Output pass: parallel across lanes; also stages tail leaders.
    for (int t = lane; t < nkept; t += 64) {
        int ip = kposL[t];
        float4 v = sbox[ip];
        float* rr = regions + ((size_t)(img * MAXDET + t)) * 5;
        rr[0] = (float)img; rr[1] = v.x; rr[2] = v.y; rr[3] = v.z; rr[4] = v.w;
        maskv[img * MAXDET + t] = 1.0f;
        leadersB[t] = v;
        leadersA[t] = (v.z - v.x) * (v.w - v.y);
    }

    // ---- Tail (R19-proven): batched. Candidates are exactly the keys < pmin
    // in desc order. q0/q1 = #keys >= pmin per half via parallel ballot-count;
    // 64 candidates per batch via per-lane merge-path binary search; boxes now
    // read from boxLds (was scattered global); leader tests per-lane; keeper
    // chain via uniform ctz + shuffle broadcast + one ballot/keeper.
    if (nkept < MAXDET) {
        u64 pmin = pminS;                              // pool = keys >= pmin
        int q0 = 0, q1 = 0;
#pragma unroll
        for (int w = 0; w < 16; ++w) {
            q0 += __popcll(__ballot(hk[(w << 6) + lane] >= pmin));
            q1 += __popcll(__ballot(hk[HALF + (w << 6) + lane] >= pmin));
        }
        for (;;) {
            const int lenA = HALF - q0, lenB = HALF - q1;
            const int rem  = lenA + lenB;
            if (rem <= 0) break;
            // lane t = t-th merged candidate; cross-diagonal binary search.
            u64  myKey = 0;
            bool fromA = false;
            if (lane < rem) {
                int lo = lane + 1 - lenB; if (lo < 0) lo = 0;
                int hi = (lane + 1 < lenA) ? lane + 1 : lenA;
                while (lo < hi) {
                    int a = (lo + hi) >> 1, b = lane + 1 - a;
                    // a too small iff untaken A[a] outranks taken B[b-1]
                    if (a < lenA && b > 0 && hk[q0 + a] > hk[HALF + q1 + b - 1]) lo = a + 1;
                    else hi = a;
                }
                int a = lo, b = lane + 1 - a;
                u64 ka = (a > 0) ? hk[q0 + a - 1] : ~0ULL;   // keys < ~0 always
                u64 kb = (b > 0) ? hk[HALF + q1 + b - 1] : ~0ULL;
                fromA = (ka < kb);          // min of last-taken = M[lane]; unique keys
                myKey = fromA ? ka : kb;
            }
            // valids form a prefix (any valid key > any invalid key).
            bool validC = (lane < rem) && (((unsigned int)(myKey >> 32)) != 0u);
            u64 vmask = __ballot(validC);
            float4 v = make_float4(0.0f, 0.0f, 0.0f, 0.0f);
            float varea = 0.0f;
            if (validC) {                   // LDS candidate loads
                v = boxLds[~(unsigned int)myKey];
                varea = (v.z - v.x) * (v.w - v.y);
            }
            // test my candidate vs all existing leaders (broadcast LDS reads)
            bool supL = false;
#pragma unroll 4
            for (int t = 0; t < nkept; ++t) {
                float4 Lb = leadersB[t];
                float  La = leadersA[t];
                float iw = fminf(Lb.z, v.z) - fmaxf(Lb.x, v.x);
                float ih = fminf(Lb.w, v.w) - fmaxf(Lb.y, v.y);
                iw = fmaxf(iw, 0.0f);
                ih = fmaxf(ih, 0.0f);
                float inter = iw * ih;
                float denom = (La + varea) - inter;
                supL = supL || ((double)inter > IOU_MID * (double)denom);
            }
            u64 mcur = vmask & ~__ballot(supL);
            while (mcur != 0ULL) {
                int il = (int)__builtin_ctzll(mcur);       // uniform
                float bx = __shfl(v.x, il, 64), by = __shfl(v.y, il, 64);
                float bz = __shfl(v.z, il, 64), bw = __shfl(v.w, il, 64);
                float ba = __shfl(varea, il, 64);
                if (lane == il) {
                    float* rr = regions + ((size_t)(img * MAXDET + nkept)) * 5;
                    rr[0] = (float)img; rr[1] = v.x; rr[2] = v.y; rr[3] = v.z; rr[4] = v.w;
                    maskv[img * MAXDET + nkept] = 1.0f;
                    leadersB[nkept] = v;
                    leadersA[nkept] = varea;
                }
                nkept++;
                if (nkept >= MAXDET) break;                // uniform
                float iw = fminf(bz, v.z) - fmaxf(bx, v.x);
                float ih = fminf(bw, v.w) - fmaxf(by, v.y);
                iw = fmaxf(iw, 0.0f);
                ih = fmaxf(ih, 0.0f);
                float inter = iw * ih;
                float denom = (ba + varea) - inter;        // keeper area first (ref order)
                bool hit = ((double)inter > IOU_MID * (double)denom);
                mcur = (mcur & (mcur - 1)) & ~__ballot(hit);
            }
            if (nkept >= MAXDET) break;
            int nv = __popcll(vmask);
            if (nv < 64) break;                            // keys exhausted
            int nA = __popcll(vmask & __ballot(fromA));
            q0 += nA;
            q1 += nv - nA;
        }
    }

    // Padding fill (d_out is poisoned before every launch).
    for (int r = nkept + lane; r < MAXDET; r += 64) {
        float* rr = regions + ((size_t)(img * MAXDET + r)) * 5;
        rr[0] = (float)img; rr[1] = 0.0f; rr[2] = 0.0f; rr[3] = 0.0f; rr[4] = 0.0f;
        maskv[img * MAXDET + r] = 0.0f;
    }
}

extern "C" void kernel_launch(void* const* d_in, const int* in_sizes, int n_in,
                              void* d_out, int out_size, void* d_ws, size_t ws_size,
                              hipStream_t stream) {
    const float* boxes  = (const float*)d_in[0];  // [8,2048,4] f32
    const float* scores = (const float*)d_in[1];  // [8,2048]   f32
    float* out = (float*)d_out;                   // 4800 f32: regions(4000) ++ mask(800)
    k_all<<<NIMG, 1024, 0, stream>>>(boxes, scores, out);
}